// Round 1
// 1378.214 us; speedup vs baseline: 1.1127x; 1.1127x over previous
//
#include <hip/hip_runtime.h>
#include <math.h>

#define N_NODES 100000
#define N_EDGES 1600000
#define D 64
#define NP 4160      // 64*64+64
#define GI3 12480    // 3*NP
#define GIN 2048     // TOPK*D
#define TOPK 32

// ---- bucketed CSR build ----
#define NB 391          // buckets of 256 dst nodes: ceil(100000/256)
#define SCAT_ITEMS 4096 // edges per k_bscatter block
#define SCAT_BLKS 391   // ceil(1600000/4096)
#define COLCAP 6144     // LDS col staging capacity (avg bucket = 4082 edges)

// ---- workspace layout (float units) ----
#define OFF_PN     0u          // 64
#define OFF_MISC   64u         // 16 (u32): [0]=cand_count [1]=thr_bin
#define OFF_IDX    80u         // 32 (int)
#define OFF_WSEL   112u        // 32
#define OFF_ZFLAT  144u        // 2048
#define OFF_NEWW   2192u       // 4160
#define OFF_GI     6400u       // 12480
#define OFF_GH     18880u      // 12480
#define OFF_HIST   31360u      // 65536 (u32)
#define OFF_Y      96896u      // 100000
#define OFF_DEG    196896u     // repurposed: bcnt(NB) @+0, bbase(NB+1) @+512, bcur(NB) @+1024
#define OFF_DINV   296896u     // 100000
#define OFF_ROWPTR 396896u     // 100001 (u32)
#define OFF_CURSOR 496898u     // unused (kept for layout stability)
#define OFF_COL    596898u     // 1600000 (int)
#define OFF_CAND   2196898u    // 100000 u64 = 200000 floats (byte off %8==0)
#define OFF_XW     2396898u    // 6400000 (ebuf overlays first 1600000 u32 during CSR build)
#define OFF_H1     8796898u    // 6400000
#define OFF_BSUM   15196898u   // 128 (u32)
#define WS_FLOATS  15197026u

__device__ __forceinline__ unsigned fkey(float f) {
    unsigned u = __float_as_uint(f);
    return u ^ ((u & 0x80000000u) ? 0xFFFFFFFFu : 0x80000000u);
}

__global__ void k_zero32(unsigned* __restrict__ p, int n) {
    int i = blockIdx.x * blockDim.x + threadIdx.x;
    if (i < n) p[i] = 0u;
}

// ---- CSR pass 1: per-block LDS histogram of dst buckets ----
__global__ void k_bcount(const int* __restrict__ dst, unsigned* __restrict__ bcnt, int ne) {
    __shared__ unsigned h[NB];
    int t = threadIdx.x;
    for (int i = t; i < NB; i += 256) h[i] = 0u;
    __syncthreads();
    int base0 = blockIdx.x * SCAT_ITEMS;
    #pragma unroll
    for (int k = 0; k < 16; ++k) {
        int i = base0 + k * 256 + t;
        if (i < ne) atomicAdd(&h[dst[i] >> 8], 1u);
    }
    __syncthreads();
    for (int i = t; i < NB; i += 256) if (h[i]) atomicAdd(&bcnt[i], h[i]);
}

// ---- CSR pass 2: one-block exclusive scan of bucket counts ----
__global__ void k_bscan(const unsigned* __restrict__ bcnt, unsigned* __restrict__ bbase,
                        unsigned* __restrict__ bcur, unsigned* __restrict__ rowptr) {
    __shared__ unsigned sc[512];
    int t = threadIdx.x;  // 512 threads
    unsigned v = (t < NB) ? bcnt[t] : 0u;
    sc[t] = v; __syncthreads();
    for (int off = 1; off < 512; off <<= 1) {
        unsigned a = (t >= off) ? sc[t - off] : 0u;
        __syncthreads();
        sc[t] += a;
        __syncthreads();
    }
    unsigned ex = sc[t] - v;   // exclusive prefix
    if (t <= NB) bbase[t] = ex;     // bbase[NB] = total
    if (t < NB) bcur[t] = ex;
    if (t == 511) rowptr[N_NODES] = sc[511];
}

// ---- CSR pass 3: LDS counting-sort 4096 edges by bucket, coalesced run flush ----
__global__ void k_bscatter(const int* __restrict__ src, const int* __restrict__ dst,
                           unsigned* __restrict__ bcur, unsigned* __restrict__ ebuf, int ne) {
    __shared__ unsigned hist[NB];
    __shared__ unsigned sc[512];
    __shared__ unsigned basel[NB];
    __shared__ unsigned lcur[NB];
    __shared__ unsigned gdst[NB];
    __shared__ unsigned sbuf[SCAT_ITEMS];
    __shared__ unsigned short sb[SCAT_ITEMS];
    int t = threadIdx.x;
    for (int i = t; i < NB; i += 256) hist[i] = 0u;
    __syncthreads();
    int base0 = blockIdx.x * SCAT_ITEMS;
    unsigned key[16]; int bk[16];
    #pragma unroll
    for (int k = 0; k < 16; ++k) {
        int i = base0 + k * 256 + t;
        if (i < ne) {
            int d = dst[i];
            bk[k] = d >> 8;
            key[k] = ((unsigned)(d & 255) << 24) | (unsigned)src[i];
            atomicAdd(&hist[bk[k]], 1u);
        } else bk[k] = -1;
    }
    __syncthreads();
    // scan hist (padded to 512) with 256 threads, 2 elems each
    {
        unsigned v0 = hist[t];
        unsigned v1 = (t + 256 < NB) ? hist[t + 256] : 0u;
        sc[t] = v0; sc[t + 256] = v1; __syncthreads();
        for (int off = 1; off < 512; off <<= 1) {
            unsigned a0 = (t >= off) ? sc[t - off] : 0u;
            unsigned a1 = (t + 256 >= off) ? sc[t + 256 - off] : 0u;
            __syncthreads();
            sc[t] += a0; sc[t + 256] += a1;
            __syncthreads();
        }
    }
    for (int i = t; i < NB; i += 256) {
        unsigned b0 = sc[i] - hist[i];
        basel[i] = b0; lcur[i] = b0;
    }
    __syncthreads();
    // reserve a contiguous global run per bucket (1 atomic per non-empty bucket)
    for (int i = t; i < NB; i += 256) if (hist[i]) gdst[i] = atomicAdd(&bcur[i], hist[i]);
    // sort items into LDS by bucket
    #pragma unroll
    for (int k = 0; k < 16; ++k) if (bk[k] >= 0) {
        unsigned p = atomicAdd(&lcur[bk[k]], 1u);
        sbuf[p] = key[k]; sb[p] = (unsigned short)bk[k];
    }
    __syncthreads();
    int cnt = min(SCAT_ITEMS, ne - base0);
    for (int j = t; j < cnt; j += 256) {
        unsigned b = sb[j];
        ebuf[gdst[b] + ((unsigned)j - basel[b])] = sbuf[j];
    }
}

// ---- CSR pass 4: one block per bucket -> deg/dinv/rowptr + col via LDS staging ----
__global__ void k_bcsr(const unsigned* __restrict__ ebuf, const unsigned* __restrict__ bbase,
                       unsigned* __restrict__ rowptr, float* __restrict__ dinv,
                       int* __restrict__ col, int n) {
    __shared__ unsigned deg[256];
    __shared__ unsigned sc[256];
    __shared__ unsigned lcur[256];
    __shared__ int colbuf[COLCAP];
    int b = blockIdx.x, t = threadIdx.x;
    int lo = b << 8;
    unsigned e0 = bbase[b], e1 = bbase[b + 1];
    deg[t] = 0u; __syncthreads();
    for (unsigned j = e0 + t; j < e1; j += 256) atomicAdd(&deg[ebuf[j] >> 24], 1u);
    __syncthreads();
    sc[t] = deg[t]; __syncthreads();
    for (int off = 1; off < 256; off <<= 1) {
        unsigned a = (t >= off) ? sc[t - off] : 0u;
        __syncthreads();
        sc[t] += a;
        __syncthreads();
    }
    unsigned lrp = sc[t] - deg[t];  // exclusive
    if (lo + t < n) {
        rowptr[lo + t] = e0 + lrp;
        dinv[lo + t] = rsqrtf((float)(deg[t] + 1u));  // +1 self loop
    }
    lcur[t] = lrp; __syncthreads();
    for (unsigned j = e0 + t; j < e1; j += 256) {
        unsigned k = ebuf[j];
        unsigned p = atomicAdd(&lcur[k >> 24], 1u);
        if (p < COLCAP) colbuf[p] = (int)(k & 0xFFFFFFu);
        else col[e0 + p] = (int)(k & 0xFFFFFFu);   // overflow fallback (statistically unreachable)
    }
    __syncthreads();
    unsigned cnt = e1 - e0;
    for (unsigned j = t; j < cnt && j < COLCAP; j += 256) col[e0 + j] = colbuf[j];
}

__global__ void k_pnorm(const float* __restrict__ p, float* __restrict__ pn,
                        unsigned* __restrict__ misc) {
    int t = threadIdx.x;  // 64 threads
    float v = p[t];
    float s = v * v;
    for (int o = 32; o; o >>= 1) s += __shfl_down(s, o, 64);
    s = __shfl(s, 0, 64);
    pn[t] = v / (sqrtf(s) + 1e-8f);
    if (t < 16) misc[t] = 0u;
}

// wave per row: y[i] = dot(h[i,:], pn); histogram of top-16 bits of flipped key
__global__ void k_y_hist(const float* __restrict__ h, const float* __restrict__ pn,
                         float* __restrict__ y, unsigned* __restrict__ hist, int n) {
    int wave = (blockIdx.x * blockDim.x + threadIdx.x) >> 6;
    int lane = threadIdx.x & 63;
    int nw = (gridDim.x * blockDim.x) >> 6;
    float p = pn[lane];
    for (int i = wave; i < n; i += nw) {
        float v = h[(size_t)i * D + lane] * p;
        for (int o = 32; o; o >>= 1) v += __shfl_down(v, o, 64);
        if (lane == 0) {
            y[i] = v;
            atomicAdd(&hist[fkey(v) >> 16], 1u);
        }
    }
}

// find threshold bin: count(key16 >= thr) >= 32, count(key16 > thr) < 32
__global__ void k_thresh(const unsigned* __restrict__ hist, unsigned* __restrict__ misc) {
    __shared__ unsigned cs[256];   // chunk suffix sums
    __shared__ unsigned s2[256];
    __shared__ int tstar;
    int t = threadIdx.x;  // 256 threads
    unsigned sum = 0;
    for (int j = 0; j < 256; ++j) sum += hist[t * 256 + j];
    cs[t] = sum; __syncthreads();
    for (int off = 1; off < 256; off <<= 1) {
        unsigned add = (t + off < 256) ? cs[t + off] : 0u;
        __syncthreads();
        cs[t] += add;
        __syncthreads();
    }
    if (cs[t] >= TOPK && (t == 255 || cs[t + 1] < TOPK)) tstar = t;
    __syncthreads();
    int ts = tstar;
    unsigned above = (ts == 255) ? 0u : cs[ts + 1];
    s2[t] = hist[ts * 256 + t]; __syncthreads();
    for (int off = 1; off < 256; off <<= 1) {
        unsigned add = (t + off < 256) ? s2[t + off] : 0u;
        __syncthreads();
        s2[t] += add;
        __syncthreads();
    }
    if (above + s2[t] >= TOPK && (t == 255 || above + s2[t + 1] < TOPK))
        misc[1] = (unsigned)(ts * 256 + t);
}

__global__ void k_compact(const float* __restrict__ y, unsigned* __restrict__ misc,
                          unsigned long long* __restrict__ cand, int n) {
    int i = blockIdx.x * blockDim.x + threadIdx.x;
    if (i >= n) return;
    unsigned thr = misc[1];
    unsigned k = fkey(y[i]);
    if ((k >> 16) >= thr) {
        unsigned pos = atomicAdd(&misc[0], 1u);
        cand[pos] = ((unsigned long long)k << 32) | (unsigned)(0xFFFFFFFFu - (unsigned)i);
    }
}

// select top-32 in exact jax.lax.top_k order (value desc, index asc) — one wave, shuffle max
__global__ void k_select(const float* __restrict__ y, const unsigned* __restrict__ misc,
                         unsigned long long* __restrict__ cand,
                         int* __restrict__ idxb, float* __restrict__ wsel) {
    int t = threadIdx.x;  // 64 threads
    int C = (int)misc[0];
    for (int k = 0; k < TOPK; ++k) {
        unsigned long long m = 0ull;
        for (int j = t; j < C; j += 64) { unsigned long long c = cand[j]; if (c > m) m = c; }
        for (int o = 32; o; o >>= 1) {
            unsigned long long other = __shfl_down(m, o, 64);
            if (other > m) m = other;
        }
        unsigned long long best = __shfl(m, 0, 64);
        for (int j = t; j < C; j += 64) if (cand[j] == best) cand[j] = 0ull;
        if (t == 0) {
            int idx = (int)(0xFFFFFFFFu - (unsigned)(best & 0xFFFFFFFFull));
            idxb[k] = idx;
            wsel[k] = tanhf(y[idx]);
        }
    }
}

__global__ void k_zflat(const float* __restrict__ h, const int* __restrict__ idxb,
                        const float* __restrict__ wsel, float* __restrict__ z) {
    int t = blockIdx.x * blockDim.x + threadIdx.x;  // 2048
    if (t < GIN) {
        int k = t & 31, d = t >> 5;
        z[t] = h[(size_t)idxb[k] * D + d] * wsel[k];  // z_flat[d*32+k] = Z[k][d]
    }
}

// wave per row: out[r] = dot(W[r,:], vec) + bias[r]; vec = concat(vecA[:lenA], vecB)
__global__ void k_mv(const float* __restrict__ W, const float* __restrict__ bias,
                     const float* __restrict__ vecA, int lenA, const float* __restrict__ vecB,
                     float* __restrict__ out, int rows, int cols) {
    extern __shared__ float v[];
    for (int j = threadIdx.x; j < cols; j += blockDim.x)
        v[j] = (j < lenA) ? vecA[j] : vecB[j - lenA];
    __syncthreads();
    int wave = (blockIdx.x * blockDim.x + threadIdx.x) >> 6;
    int lane = threadIdx.x & 63;
    if (wave >= rows) return;
    const float4* Wr = (const float4*)(W + (size_t)wave * cols);
    int n4 = cols >> 2;
    float acc = 0.f;
    for (int j = lane; j < n4; j += 64) {
        float4 w4 = Wr[j];
        acc += w4.x * v[4 * j] + w4.y * v[4 * j + 1] + w4.z * v[4 * j + 2] + w4.w * v[4 * j + 3];
    }
    for (int o = 32; o; o >>= 1) acc += __shfl_down(acc, o, 64);
    if (lane == 0) out[wave] = acc + bias[wave];
}

__global__ void k_gru(const float* __restrict__ gi, const float* __restrict__ gh,
                      const float* __restrict__ w, const float* __restrict__ b,
                      float* __restrict__ neww) {
    int j = blockIdx.x * blockDim.x + threadIdx.x;
    if (j >= NP) return;
    float r = 1.f / (1.f + expf(-(gi[j] + gh[j])));
    float z = 1.f / (1.f + expf(-(gi[NP + j] + gh[NP + j])));
    float n = tanhf(gi[2 * NP + j] + r * gh[2 * NP + j]);
    float h0 = (j < 4096) ? w[j] : b[j - 4096];
    neww[j] = (1.f - z) * n + z * h0;
}

// xw[i][o] = sum_d h[i][d] * neww[o*64+d]
__global__ void k_xw(const float* __restrict__ h, const float* __restrict__ neww,
                     float* __restrict__ xw, int n) {
    __shared__ float WT[64 * 64];  // WT[d*64+o] = weight[o][d]
    for (int t = threadIdx.x; t < 4096; t += blockDim.x) {
        int o = t >> 6, d = t & 63;
        WT[d * 64 + o] = neww[t];
    }
    __syncthreads();
    int wave = (blockIdx.x * blockDim.x + threadIdx.x) >> 6;
    int lane = threadIdx.x & 63;
    int nw = (gridDim.x * blockDim.x) >> 6;
    for (int i = wave; i < n; i += nw) {
        float hv = h[(size_t)i * D + lane];
        float acc = 0.f;
        #pragma unroll 16
        for (int d = 0; d < 64; ++d) {
            float hd = __shfl(hv, d, 64);
            acc += hd * WT[d * 64 + lane];
        }
        xw[(size_t)i * D + lane] = acc;
    }
}

// wave per node: out[v][o] = bias[o] + dinv[v]*(dinv[v]*xw[v][o] + sum_e dinv[s]*xw[s][o])
__global__ void k_agg(const float* __restrict__ xw, const float* __restrict__ dinv,
                      const unsigned* __restrict__ rowptr, const int* __restrict__ col,
                      const float* __restrict__ neww, float* __restrict__ out,
                      int n, int relu) {
    int wave = (blockIdx.x * blockDim.x + threadIdx.x) >> 6;
    int lane = threadIdx.x & 63;
    int nw = (gridDim.x * blockDim.x) >> 6;
    float bias = neww[4096 + lane];
    for (int v = wave; v < n; v += nw) {
        unsigned p0 = rowptr[v], p1 = rowptr[v + 1];
        float dv = dinv[v];
        float acc = dv * xw[(size_t)v * D + lane];
        for (unsigned base = p0; base < p1; base += 64) {
            int cnt = (int)min(64u, p1 - base);
            int s = 0; float ds = 0.f;
            if (lane < cnt) { s = col[base + lane]; ds = dinv[s]; }
            for (int j = 0; j < cnt; ++j) {
                int sj = __shfl(s, j, 64);
                float dsj = __shfl(ds, j, 64);
                acc += dsj * xw[(size_t)sj * D + lane];
            }
        }
        float r = bias + dv * acc;
        if (relu) r = fmaxf(r, 0.f);
        out[(size_t)v * D + lane] = r;
    }
}

extern "C" void kernel_launch(void* const* d_in, const int* in_sizes, int n_in,
                              void* d_out, int out_size, void* d_ws, size_t ws_size,
                              hipStream_t stream) {
    if (ws_size < (size_t)WS_FLOATS * 4) return;  // workspace too small: fail cleanly

    const float* x = (const float*)d_in[0];
    const int* src = (const int*)d_in[1];
    const int* dst = src + N_EDGES;
    const float* P[2]   = {(const float*)d_in[2],  (const float*)d_in[3]};
    const float* W[2]   = {(const float*)d_in[4],  (const float*)d_in[6]};
    const float* B[2]   = {(const float*)d_in[5],  (const float*)d_in[7]};
    const float* WIH[2] = {(const float*)d_in[8],  (const float*)d_in[12]};
    const float* WHH[2] = {(const float*)d_in[9],  (const float*)d_in[13]};
    const float* BIH[2] = {(const float*)d_in[10], (const float*)d_in[14]};
    const float* BHH[2] = {(const float*)d_in[11], (const float*)d_in[15]};

    float* ws = (float*)d_ws;
    float* pn = ws + OFF_PN;
    unsigned* misc = (unsigned*)(ws + OFF_MISC);
    int* idxb = (int*)(ws + OFF_IDX);
    float* wsel = ws + OFF_WSEL;
    float* zflat = ws + OFF_ZFLAT;
    float* neww = ws + OFF_NEWW;
    float* gi = ws + OFF_GI;
    float* gh = ws + OFF_GH;
    unsigned* hist = (unsigned*)(ws + OFF_HIST);
    float* y = ws + OFF_Y;
    unsigned* bcnt  = (unsigned*)(ws + OFF_DEG);
    unsigned* bbase = (unsigned*)(ws + OFF_DEG) + 512;
    unsigned* bcur  = (unsigned*)(ws + OFF_DEG) + 1024;
    float* dinv = ws + OFF_DINV;
    unsigned* rowptr = (unsigned*)(ws + OFF_ROWPTR);
    int* col = (int*)(ws + OFF_COL);
    unsigned long long* cand = (unsigned long long*)(ws + OFF_CAND);
    float* xw = ws + OFF_XW;
    unsigned* ebuf = (unsigned*)(ws + OFF_XW);  // overlays xw; dead before k_xw runs
    float* h1 = ws + OFF_H1;
    float* out = (float*)d_out;

    // ---- bucketed CSR build (shared by both layers) ----
    hipLaunchKernelGGL(k_zero32, dim3((NB + 255) / 256), dim3(256), 0, stream, bcnt, NB);
    hipLaunchKernelGGL(k_bcount, dim3(SCAT_BLKS), dim3(256), 0, stream, dst, bcnt, N_EDGES);
    hipLaunchKernelGGL(k_bscan, dim3(1), dim3(512), 0, stream, bcnt, bbase, bcur, rowptr);
    hipLaunchKernelGGL(k_bscatter, dim3(SCAT_BLKS), dim3(256), 0, stream, src, dst, bcur, ebuf, N_EDGES);
    hipLaunchKernelGGL(k_bcsr, dim3(NB), dim3(256), 0, stream, ebuf, bbase, rowptr, dinv, col, N_NODES);

    for (int l = 0; l < 2; ++l) {
        const float* h = (l == 0) ? x : h1;
        float* ho = (l == 0) ? h1 : out;
        hipLaunchKernelGGL(k_zero32, dim3(256), dim3(256), 0, stream, hist, 65536);
        hipLaunchKernelGGL(k_pnorm, dim3(1), dim3(64), 0, stream, P[l], pn, misc);
        hipLaunchKernelGGL(k_y_hist, dim3(1024), dim3(256), 0, stream, h, pn, y, hist, N_NODES);
        hipLaunchKernelGGL(k_thresh, dim3(1), dim3(256), 0, stream, hist, misc);
        hipLaunchKernelGGL(k_compact, dim3((N_NODES + 255) / 256), dim3(256), 0, stream, y, misc, cand, N_NODES);
        hipLaunchKernelGGL(k_select, dim3(1), dim3(64), 0, stream, y, misc, cand, idxb, wsel);
        hipLaunchKernelGGL(k_zflat, dim3(8), dim3(256), 0, stream, h, idxb, wsel, zflat);
        hipLaunchKernelGGL(k_mv, dim3(GI3 / 4), dim3(256), GIN * 4, stream,
                           WIH[l], BIH[l], zflat, GIN, zflat, gi, GI3, GIN);
        hipLaunchKernelGGL(k_mv, dim3(GI3 / 4), dim3(256), NP * 4, stream,
                           WHH[l], BHH[l], W[l], 4096, B[l], gh, GI3, NP);
        hipLaunchKernelGGL(k_gru, dim3((NP + 255) / 256), dim3(256), 0, stream, gi, gh, W[l], B[l], neww);
        hipLaunchKernelGGL(k_xw, dim3(2048), dim3(256), 0, stream, h, neww, xw, N_NODES);
        hipLaunchKernelGGL(k_agg, dim3(4096), dim3(256), 0, stream, xw, dinv, rowptr, col, neww, ho,
                           N_NODES, (l == 0) ? 1 : 0);
    }
}

// Round 2
// 1361.522 us; speedup vs baseline: 1.1263x; 1.0123x over previous
//
#include <hip/hip_runtime.h>
#include <math.h>

#define N_NODES 100000
#define N_EDGES 1600000
#define D 64
#define NP 4160      // 64*64+64
#define GI3 12480    // 3*NP
#define GIN 2048     // TOPK*D
#define TOPK 32
#define MV_BLKS 3120 // GI3/4 waves-per-block

// ---- bucketed CSR build ----
#define NB 391          // buckets of 256 dst nodes: ceil(100000/256)
#define SCAT_ITEMS 4096 // edges per k_bscatter block
#define SCAT_BLKS 391   // ceil(1600000/4096)
#define COLCAP 6144     // LDS col staging capacity (avg bucket = 4082 edges)

// ---- workspace layout (float units) ----
#define OFF_PN     0u          // 64
#define OFF_MISC   64u         // 16 (u32): [0]=cand_count [1]=thr_bin
#define OFF_IDX    80u         // 32 (int)
#define OFF_WSEL   112u        // 32
#define OFF_ZFLAT  144u        // 2048
#define OFF_NEWW   2192u       // 4160
#define OFF_GI     6400u       // 12480
#define OFF_GH     18880u      // 12480
#define OFF_HIST   31360u      // 65536 (u32)
#define OFF_Y      96896u      // 100000
#define OFF_DEG    196896u     // repurposed: bcnt(NB) @+0, bbase(NB+1) @+512, bcur(NB) @+1024
#define OFF_DINV   296896u     // 100000
#define OFF_ROWPTR 396896u     // 100001 (u32)
#define OFF_CURSOR 496898u     // unused (kept for layout stability)
#define OFF_COL    596898u     // 1600000 (int)
#define OFF_CAND   2196898u    // 100000 u64 = 200000 floats (byte off %8==0)
#define OFF_XW     2396898u    // 6400000 (ebuf overlays first 1600000 u32 during CSR build)
#define OFF_H1     8796898u    // 6400000
#define OFF_BSUM   15196898u   // 128 (u32)
#define WS_FLOATS  15197026u

__device__ __forceinline__ unsigned fkey(float f) {
    unsigned u = __float_as_uint(f);
    return u ^ ((u & 0x80000000u) ? 0xFFFFFFFFu : 0x80000000u);
}

__global__ void k_zero32(unsigned* __restrict__ p, int n) {
    int i = blockIdx.x * blockDim.x + threadIdx.x;
    if (i < n) p[i] = 0u;
}

// ---- CSR pass 1: per-block LDS histogram of dst buckets ----
__global__ void k_bcount(const int* __restrict__ dst, unsigned* __restrict__ bcnt, int ne) {
    __shared__ unsigned h[NB];
    int t = threadIdx.x;
    for (int i = t; i < NB; i += 256) h[i] = 0u;
    __syncthreads();
    int base0 = blockIdx.x * SCAT_ITEMS;
    #pragma unroll
    for (int k = 0; k < 16; ++k) {
        int i = base0 + k * 256 + t;
        if (i < ne) atomicAdd(&h[dst[i] >> 8], 1u);
    }
    __syncthreads();
    for (int i = t; i < NB; i += 256) if (h[i]) atomicAdd(&bcnt[i], h[i]);
}

// ---- CSR pass 2: one-block exclusive scan of bucket counts ----
__global__ void k_bscan(const unsigned* __restrict__ bcnt, unsigned* __restrict__ bbase,
                        unsigned* __restrict__ bcur, unsigned* __restrict__ rowptr) {
    __shared__ unsigned sc[512];
    int t = threadIdx.x;  // 512 threads
    unsigned v = (t < NB) ? bcnt[t] : 0u;
    sc[t] = v; __syncthreads();
    for (int off = 1; off < 512; off <<= 1) {
        unsigned a = (t >= off) ? sc[t - off] : 0u;
        __syncthreads();
        sc[t] += a;
        __syncthreads();
    }
    unsigned ex = sc[t] - v;   // exclusive prefix
    if (t <= NB) bbase[t] = ex;     // bbase[NB] = total
    if (t < NB) bcur[t] = ex;
    if (t == 511) rowptr[N_NODES] = sc[511];
}

// ---- CSR pass 3: LDS counting-sort 4096 edges by bucket, coalesced run flush ----
__global__ void k_bscatter(const int* __restrict__ src, const int* __restrict__ dst,
                           unsigned* __restrict__ bcur, unsigned* __restrict__ ebuf, int ne) {
    __shared__ unsigned hist[NB];
    __shared__ unsigned sc[512];
    __shared__ unsigned basel[NB];
    __shared__ unsigned lcur[NB];
    __shared__ unsigned gdst[NB];
    __shared__ unsigned sbuf[SCAT_ITEMS];
    __shared__ unsigned short sb[SCAT_ITEMS];
    int t = threadIdx.x;
    for (int i = t; i < NB; i += 256) hist[i] = 0u;
    __syncthreads();
    int base0 = blockIdx.x * SCAT_ITEMS;
    unsigned key[16]; int bk[16];
    #pragma unroll
    for (int k = 0; k < 16; ++k) {
        int i = base0 + k * 256 + t;
        if (i < ne) {
            int d = dst[i];
            bk[k] = d >> 8;
            key[k] = ((unsigned)(d & 255) << 24) | (unsigned)src[i];
            atomicAdd(&hist[bk[k]], 1u);
        } else bk[k] = -1;
    }
    __syncthreads();
    // scan hist (padded to 512) with 256 threads, 2 elems each
    {
        unsigned v0 = hist[t];
        unsigned v1 = (t + 256 < NB) ? hist[t + 256] : 0u;
        sc[t] = v0; sc[t + 256] = v1; __syncthreads();
        for (int off = 1; off < 512; off <<= 1) {
            unsigned a0 = (t >= off) ? sc[t - off] : 0u;
            unsigned a1 = (t + 256 >= off) ? sc[t + 256 - off] : 0u;
            __syncthreads();
            sc[t] += a0; sc[t + 256] += a1;
            __syncthreads();
        }
    }
    for (int i = t; i < NB; i += 256) {
        unsigned b0 = sc[i] - hist[i];
        basel[i] = b0; lcur[i] = b0;
    }
    __syncthreads();
    // reserve a contiguous global run per bucket (1 atomic per non-empty bucket)
    for (int i = t; i < NB; i += 256) if (hist[i]) gdst[i] = atomicAdd(&bcur[i], hist[i]);
    // sort items into LDS by bucket
    #pragma unroll
    for (int k = 0; k < 16; ++k) if (bk[k] >= 0) {
        unsigned p = atomicAdd(&lcur[bk[k]], 1u);
        sbuf[p] = key[k]; sb[p] = (unsigned short)bk[k];
    }
    __syncthreads();
    int cnt = min(SCAT_ITEMS, ne - base0);
    for (int j = t; j < cnt; j += 256) {
        unsigned b = sb[j];
        ebuf[gdst[b] + ((unsigned)j - basel[b])] = sbuf[j];
    }
}

// ---- CSR pass 4: one block per bucket -> deg/dinv/rowptr + col via LDS staging ----
__global__ void k_bcsr(const unsigned* __restrict__ ebuf, const unsigned* __restrict__ bbase,
                       unsigned* __restrict__ rowptr, float* __restrict__ dinv,
                       int* __restrict__ col, int n) {
    __shared__ unsigned deg[256];
    __shared__ unsigned sc[256];
    __shared__ unsigned lcur[256];
    __shared__ int colbuf[COLCAP];
    int b = blockIdx.x, t = threadIdx.x;
    int lo = b << 8;
    unsigned e0 = bbase[b], e1 = bbase[b + 1];
    deg[t] = 0u; __syncthreads();
    for (unsigned j = e0 + t; j < e1; j += 256) atomicAdd(&deg[ebuf[j] >> 24], 1u);
    __syncthreads();
    sc[t] = deg[t]; __syncthreads();
    for (int off = 1; off < 256; off <<= 1) {
        unsigned a = (t >= off) ? sc[t - off] : 0u;
        __syncthreads();
        sc[t] += a;
        __syncthreads();
    }
    unsigned lrp = sc[t] - deg[t];  // exclusive
    if (lo + t < n) {
        rowptr[lo + t] = e0 + lrp;
        dinv[lo + t] = rsqrtf((float)(deg[t] + 1u));  // +1 self loop
    }
    lcur[t] = lrp; __syncthreads();
    for (unsigned j = e0 + t; j < e1; j += 256) {
        unsigned k = ebuf[j];
        unsigned p = atomicAdd(&lcur[k >> 24], 1u);
        if (p < COLCAP) colbuf[p] = (int)(k & 0xFFFFFFu);
        else col[e0 + p] = (int)(k & 0xFFFFFFu);   // overflow fallback (statistically unreachable)
    }
    __syncthreads();
    unsigned cnt = e1 - e0;
    for (unsigned j = t; j < cnt && j < COLCAP; j += 256) col[e0 + j] = colbuf[j];
}

// p-normalize (block 0, wave 0) + zero the 65536-bin histogram (whole grid: 256x256)
__global__ void k_pnorm_zh(const float* __restrict__ p, float* __restrict__ pn,
                           unsigned* __restrict__ misc, unsigned* __restrict__ hist) {
    int g = blockIdx.x * blockDim.x + threadIdx.x;
    hist[g] = 0u;
    if (blockIdx.x == 0) {
        int t = threadIdx.x;
        if (t < 64) {
            float v = p[t];
            float s = v * v;
            for (int o = 32; o; o >>= 1) s += __shfl_down(s, o, 64);
            s = __shfl(s, 0, 64);
            pn[t] = v / (sqrtf(s) + 1e-8f);
        }
        if (t < 16) misc[t] = 0u;
    }
}

// wave per 4 rows (ILP): y[i] = dot(h[i,:], pn); histogram of top-16 bits of flipped key
__global__ void k_y_hist(const float* __restrict__ h, const float* __restrict__ pn,
                         float* __restrict__ y, unsigned* __restrict__ hist, int n) {
    int wave = (blockIdx.x * blockDim.x + threadIdx.x) >> 6;
    int lane = threadIdx.x & 63;
    int nw = (gridDim.x * blockDim.x) >> 6;
    float p = pn[lane];
    for (int i = wave; i < n; i += 4 * nw) {
        int i1 = i + nw, i2 = i + 2 * nw, i3 = i + 3 * nw;
        float v0 = h[(size_t)i * D + lane] * p;
        float v1 = (i1 < n) ? h[(size_t)i1 * D + lane] * p : 0.f;
        float v2 = (i2 < n) ? h[(size_t)i2 * D + lane] * p : 0.f;
        float v3 = (i3 < n) ? h[(size_t)i3 * D + lane] * p : 0.f;
        #pragma unroll
        for (int o = 32; o; o >>= 1) {
            v0 += __shfl_down(v0, o, 64);
            v1 += __shfl_down(v1, o, 64);
            v2 += __shfl_down(v2, o, 64);
            v3 += __shfl_down(v3, o, 64);
        }
        if (lane == 0) {
            y[i] = v0; atomicAdd(&hist[fkey(v0) >> 16], 1u);
            if (i1 < n) { y[i1] = v1; atomicAdd(&hist[fkey(v1) >> 16], 1u); }
            if (i2 < n) { y[i2] = v2; atomicAdd(&hist[fkey(v2) >> 16], 1u); }
            if (i3 < n) { y[i3] = v3; atomicAdd(&hist[fkey(v3) >> 16], 1u); }
        }
    }
}

// find threshold bin: count(key16 >= thr) >= 32, count(key16 > thr) < 32
__global__ void k_thresh(const unsigned* __restrict__ hist, unsigned* __restrict__ misc) {
    __shared__ unsigned cs[256];   // chunk suffix sums
    __shared__ unsigned s2[256];
    __shared__ int tstar;
    int t = threadIdx.x;  // 256 threads
    unsigned sum = 0;
    for (int j = 0; j < 256; ++j) sum += hist[t * 256 + j];
    cs[t] = sum; __syncthreads();
    for (int off = 1; off < 256; off <<= 1) {
        unsigned add = (t + off < 256) ? cs[t + off] : 0u;
        __syncthreads();
        cs[t] += add;
        __syncthreads();
    }
    if (cs[t] >= TOPK && (t == 255 || cs[t + 1] < TOPK)) tstar = t;
    __syncthreads();
    int ts = tstar;
    unsigned above = (ts == 255) ? 0u : cs[ts + 1];
    s2[t] = hist[ts * 256 + t]; __syncthreads();
    for (int off = 1; off < 256; off <<= 1) {
        unsigned add = (t + off < 256) ? s2[t + off] : 0u;
        __syncthreads();
        s2[t] += add;
        __syncthreads();
    }
    if (above + s2[t] >= TOPK && (t == 255 || above + s2[t + 1] < TOPK))
        misc[1] = (unsigned)(ts * 256 + t);
}

__global__ void k_compact(const float* __restrict__ y, unsigned* __restrict__ misc,
                          unsigned long long* __restrict__ cand, int n) {
    int i = blockIdx.x * blockDim.x + threadIdx.x;
    if (i >= n) return;
    unsigned thr = misc[1];
    unsigned k = fkey(y[i]);
    if ((k >> 16) >= thr) {
        unsigned pos = atomicAdd(&misc[0], 1u);
        cand[pos] = ((unsigned long long)k << 32) | (unsigned)(0xFFFFFFFFu - (unsigned)i);
    }
}

// select top-32 in exact jax.lax.top_k order (value desc, index asc) — one wave, shuffle max
__global__ void k_select(const float* __restrict__ y, const unsigned* __restrict__ misc,
                         unsigned long long* __restrict__ cand,
                         int* __restrict__ idxb, float* __restrict__ wsel) {
    int t = threadIdx.x;  // 64 threads
    int C = (int)misc[0];
    for (int k = 0; k < TOPK; ++k) {
        unsigned long long m = 0ull;
        for (int j = t; j < C; j += 64) { unsigned long long c = cand[j]; if (c > m) m = c; }
        for (int o = 32; o; o >>= 1) {
            unsigned long long other = __shfl_down(m, o, 64);
            if (other > m) m = other;
        }
        unsigned long long best = __shfl(m, 0, 64);
        for (int j = t; j < C; j += 64) if (cand[j] == best) cand[j] = 0ull;
        if (t == 0) {
            int idx = (int)(0xFFFFFFFFu - (unsigned)(best & 0xFFFFFFFFull));
            idxb[k] = idx;
            wsel[k] = tanhf(y[idx]);
        }
    }
}

__global__ void k_zflat(const float* __restrict__ h, const int* __restrict__ idxb,
                        const float* __restrict__ wsel, float* __restrict__ z) {
    int t = blockIdx.x * blockDim.x + threadIdx.x;  // 2048
    if (t < GIN) {
        int k = t & 31, d = t >> 5;
        z[t] = h[(size_t)idxb[k] * D + d] * wsel[k];  // z_flat[d*32+k] = Z[k][d]
    }
}

// two independent matvecs (gi, gh) fused into one dispatch; seg by blockIdx
// out[r] = dot(W[r,:], vec) + bias[r]; vec = concat(vecA[:lenA], vecB)
__global__ void k_mv2(const float* __restrict__ W0, const float* __restrict__ bia0,
                      const float* __restrict__ vA0, int lenA0, const float* __restrict__ vB0,
                      float* __restrict__ out0, int cols0,
                      const float* __restrict__ W1, const float* __restrict__ bia1,
                      const float* __restrict__ vA1, int lenA1, const float* __restrict__ vB1,
                      float* __restrict__ out1, int cols1) {
    extern __shared__ float v[];
    int seg = (blockIdx.x >= MV_BLKS);
    const float* W    = seg ? W1   : W0;
    const float* bias = seg ? bia1 : bia0;
    const float* vA   = seg ? vA1  : vA0;
    const float* vB   = seg ? vB1  : vB0;
    float* out        = seg ? out1 : out0;
    int lenA          = seg ? lenA1 : lenA0;
    int cols          = seg ? cols1 : cols0;
    int lb = blockIdx.x - (seg ? MV_BLKS : 0);
    for (int j = threadIdx.x; j < cols; j += blockDim.x)
        v[j] = (j < lenA) ? vA[j] : vB[j - lenA];
    __syncthreads();
    int row = ((lb * blockDim.x + threadIdx.x) >> 6);
    int lane = threadIdx.x & 63;
    if (row >= GI3) return;
    const float4* Wr = (const float4*)(W + (size_t)row * cols);
    int n4 = cols >> 2;
    float acc = 0.f;
    for (int j = lane; j < n4; j += 64) {
        float4 w4 = Wr[j];
        acc += w4.x * v[4 * j] + w4.y * v[4 * j + 1] + w4.z * v[4 * j + 2] + w4.w * v[4 * j + 3];
    }
    for (int o = 32; o; o >>= 1) acc += __shfl_down(acc, o, 64);
    if (lane == 0) out[row] = acc + bias[row];
}

__global__ void k_gru(const float* __restrict__ gi, const float* __restrict__ gh,
                      const float* __restrict__ w, const float* __restrict__ b,
                      float* __restrict__ neww) {
    int j = blockIdx.x * blockDim.x + threadIdx.x;
    if (j >= NP) return;
    float r = 1.f / (1.f + expf(-(gi[j] + gh[j])));
    float z = 1.f / (1.f + expf(-(gi[NP + j] + gh[NP + j])));
    float n = tanhf(gi[2 * NP + j] + r * gh[2 * NP + j]);
    float h0 = (j < 4096) ? w[j] : b[j - 4096];
    neww[j] = (1.f - z) * n + z * h0;
}

// sxw[i][o] = dinv[i] * sum_d h[i][d] * neww[o*64+d]   (dinv folded into producer)
__global__ void k_xw(const float* __restrict__ h, const float* __restrict__ neww,
                     const float* __restrict__ dinv, float* __restrict__ sxw, int n) {
    __shared__ float WT[64 * 64];  // WT[d*64+o] = weight[o][d]
    for (int t = threadIdx.x; t < 4096; t += blockDim.x) {
        int o = t >> 6, d = t & 63;
        WT[d * 64 + o] = neww[t];
    }
    __syncthreads();
    int wave = (blockIdx.x * blockDim.x + threadIdx.x) >> 6;
    int lane = threadIdx.x & 63;
    int nw = (gridDim.x * blockDim.x) >> 6;
    for (int i = wave; i < n; i += nw) {
        float hv = h[(size_t)i * D + lane];
        float acc = 0.f;
        #pragma unroll 16
        for (int d = 0; d < 64; ++d) {
            float hd = __shfl(hv, d, 64);
            acc += hd * WT[d * 64 + lane];
        }
        sxw[(size_t)i * D + lane] = dinv[i] * acc;
    }
}

// wave per node: out[v][o] = bias[o] + dinv[v]*(sxw[v][o] + sum_e sxw[s][o])
__global__ void k_agg(const float* __restrict__ sxw, const float* __restrict__ dinv,
                      const unsigned* __restrict__ rowptr, const int* __restrict__ col,
                      const float* __restrict__ neww, float* __restrict__ out,
                      int n, int relu) {
    int wave = (blockIdx.x * blockDim.x + threadIdx.x) >> 6;
    int lane = threadIdx.x & 63;
    int nw = (gridDim.x * blockDim.x) >> 6;
    float bias = neww[4096 + lane];
    for (int v = wave; v < n; v += nw) {
        unsigned p0 = rowptr[v], p1 = rowptr[v + 1];
        float dv = dinv[v];
        float acc = sxw[(size_t)v * D + lane];
        for (unsigned base = p0; base < p1; base += 64) {
            int cnt = (int)min(64u, p1 - base);
            int s = 0;
            if (lane < cnt) s = col[base + lane];
            for (int j = 0; j < cnt; ++j) {
                int sj = __shfl(s, j, 64);
                acc += sxw[(size_t)sj * D + lane];
            }
        }
        float r = bias + dv * acc;
        if (relu) r = fmaxf(r, 0.f);
        out[(size_t)v * D + lane] = r;
    }
}

extern "C" void kernel_launch(void* const* d_in, const int* in_sizes, int n_in,
                              void* d_out, int out_size, void* d_ws, size_t ws_size,
                              hipStream_t stream) {
    if (ws_size < (size_t)WS_FLOATS * 4) return;  // workspace too small: fail cleanly

    const float* x = (const float*)d_in[0];
    const int* src = (const int*)d_in[1];
    const int* dst = src + N_EDGES;
    const float* P[2]   = {(const float*)d_in[2],  (const float*)d_in[3]};
    const float* W[2]   = {(const float*)d_in[4],  (const float*)d_in[6]};
    const float* B[2]   = {(const float*)d_in[5],  (const float*)d_in[7]};
    const float* WIH[2] = {(const float*)d_in[8],  (const float*)d_in[12]};
    const float* WHH[2] = {(const float*)d_in[9],  (const float*)d_in[13]};
    const float* BIH[2] = {(const float*)d_in[10], (const float*)d_in[14]};
    const float* BHH[2] = {(const float*)d_in[11], (const float*)d_in[15]};

    float* ws = (float*)d_ws;
    float* pn = ws + OFF_PN;
    unsigned* misc = (unsigned*)(ws + OFF_MISC);
    int* idxb = (int*)(ws + OFF_IDX);
    float* wsel = ws + OFF_WSEL;
    float* zflat = ws + OFF_ZFLAT;
    float* neww = ws + OFF_NEWW;
    float* gi = ws + OFF_GI;
    float* gh = ws + OFF_GH;
    unsigned* hist = (unsigned*)(ws + OFF_HIST);
    float* y = ws + OFF_Y;
    unsigned* bcnt  = (unsigned*)(ws + OFF_DEG);
    unsigned* bbase = (unsigned*)(ws + OFF_DEG) + 512;
    unsigned* bcur  = (unsigned*)(ws + OFF_DEG) + 1024;
    float* dinv = ws + OFF_DINV;
    unsigned* rowptr = (unsigned*)(ws + OFF_ROWPTR);
    int* col = (int*)(ws + OFF_COL);
    unsigned long long* cand = (unsigned long long*)(ws + OFF_CAND);
    float* xw = ws + OFF_XW;
    unsigned* ebuf = (unsigned*)(ws + OFF_XW);  // overlays xw; dead before k_xw runs
    float* h1 = ws + OFF_H1;
    float* out = (float*)d_out;

    // ---- bucketed CSR build (shared by both layers) ----
    hipLaunchKernelGGL(k_zero32, dim3((NB + 255) / 256), dim3(256), 0, stream, bcnt, NB);
    hipLaunchKernelGGL(k_bcount, dim3(SCAT_BLKS), dim3(256), 0, stream, dst, bcnt, N_EDGES);
    hipLaunchKernelGGL(k_bscan, dim3(1), dim3(512), 0, stream, bcnt, bbase, bcur, rowptr);
    hipLaunchKernelGGL(k_bscatter, dim3(SCAT_BLKS), dim3(256), 0, stream, src, dst, bcur, ebuf, N_EDGES);
    hipLaunchKernelGGL(k_bcsr, dim3(NB), dim3(256), 0, stream, ebuf, bbase, rowptr, dinv, col, N_NODES);

    for (int l = 0; l < 2; ++l) {
        const float* h = (l == 0) ? x : h1;
        float* ho = (l == 0) ? h1 : out;
        hipLaunchKernelGGL(k_pnorm_zh, dim3(256), dim3(256), 0, stream, P[l], pn, misc, hist);
        hipLaunchKernelGGL(k_y_hist, dim3(1024), dim3(256), 0, stream, h, pn, y, hist, N_NODES);
        hipLaunchKernelGGL(k_thresh, dim3(1), dim3(256), 0, stream, hist, misc);
        hipLaunchKernelGGL(k_compact, dim3((N_NODES + 255) / 256), dim3(256), 0, stream, y, misc, cand, N_NODES);
        hipLaunchKernelGGL(k_select, dim3(1), dim3(64), 0, stream, y, misc, cand, idxb, wsel);
        hipLaunchKernelGGL(k_zflat, dim3(8), dim3(256), 0, stream, h, idxb, wsel, zflat);
        hipLaunchKernelGGL(k_mv2, dim3(2 * MV_BLKS), dim3(256), NP * 4, stream,
                           WIH[l], BIH[l], zflat, GIN, zflat, gi, GIN,
                           WHH[l], BHH[l], W[l], 4096, B[l], gh, NP);
        hipLaunchKernelGGL(k_gru, dim3((NP + 255) / 256), dim3(256), 0, stream, gi, gh, W[l], B[l], neww);
        hipLaunchKernelGGL(k_xw, dim3(2048), dim3(256), 0, stream, h, neww, dinv, xw, N_NODES);
        hipLaunchKernelGGL(k_agg, dim3(4096), dim3(256), 0, stream, xw, dinv, rowptr, col, neww, ho,
                           N_NODES, (l == 0) ? 1 : 0);
    }
}

// Round 3
// 1338.888 us; speedup vs baseline: 1.1454x; 1.0169x over previous
//
#include <hip/hip_runtime.h>
#include <math.h>

#define N_NODES 100000
#define N_EDGES 1600000
#define D 64
#define NP 4160      // 64*64+64
#define GI3 12480    // 3*NP
#define GIN 2048     // TOPK*D
#define TOPK 32
#define MV_BLKS 3120 // GI3/4 waves-per-block
#define TCAP 2048    // LDS candidate capacity in k_topsel

// ---- bucketed CSR build ----
#define NB 391          // buckets of 256 dst nodes: ceil(100000/256)
#define SCAT_ITEMS 4096 // edges per k_bscatter block
#define SCAT_BLKS 391   // ceil(1600000/4096)
#define COLCAP 6144     // LDS col staging capacity (avg bucket = 4082 edges)

// ---- workspace layout (float units) ----
#define OFF_PN     0u          // 64
#define OFF_MISC   64u         // 16 (u32)
#define OFF_IDX    80u         // 32 (int)
#define OFF_WSEL   112u        // 32
#define OFF_ZFLAT  144u        // 2048
#define OFF_NEWW   2192u       // 4160
#define OFF_GI     6400u       // 12480
#define OFF_GH     18880u      // 12480
#define OFF_HIST   31360u      // 65536 (u32)
#define OFF_Y      96896u      // 100000
#define OFF_DEG    196896u     // repurposed: bcnt(NB) @+0, bbase(NB+1) @+512, bcur(NB) @+1024
#define OFF_DINV   296896u     // 100000
#define OFF_ROWPTR 396896u     // 100001 (u32)
#define OFF_CURSOR 496898u     // unused (kept for layout stability)
#define OFF_COL    596898u     // 1600000 (int)
#define OFF_CAND   2196898u    // 100000 u64 = 200000 floats (byte off %8==0)
#define OFF_XW     2396898u    // 6400000 (ebuf overlays first 1600000 u32 during CSR build)
#define OFF_H1     8796898u    // 6400000
#define OFF_BSUM   15196898u   // 128 (u32)
#define WS_FLOATS  15197026u

__device__ __forceinline__ unsigned fkey(float f) {
    unsigned u = __float_as_uint(f);
    return u ^ ((u & 0x80000000u) ? 0xFFFFFFFFu : 0x80000000u);
}

__global__ void k_zero32(unsigned* __restrict__ p, int n) {
    int i = blockIdx.x * blockDim.x + threadIdx.x;
    if (i < n) p[i] = 0u;
}

// ---- CSR pass 1: per-block LDS histogram of dst buckets ----
__global__ void k_bcount(const int* __restrict__ dst, unsigned* __restrict__ bcnt, int ne) {
    __shared__ unsigned h[NB];
    int t = threadIdx.x;
    for (int i = t; i < NB; i += 256) h[i] = 0u;
    __syncthreads();
    int base0 = blockIdx.x * SCAT_ITEMS;
    #pragma unroll
    for (int k = 0; k < 16; ++k) {
        int i = base0 + k * 256 + t;
        if (i < ne) atomicAdd(&h[dst[i] >> 8], 1u);
    }
    __syncthreads();
    for (int i = t; i < NB; i += 256) if (h[i]) atomicAdd(&bcnt[i], h[i]);
}

// ---- CSR pass 2: one-block exclusive scan of bucket counts ----
__global__ void k_bscan(const unsigned* __restrict__ bcnt, unsigned* __restrict__ bbase,
                        unsigned* __restrict__ bcur, unsigned* __restrict__ rowptr) {
    __shared__ unsigned sc[512];
    int t = threadIdx.x;  // 512 threads
    unsigned v = (t < NB) ? bcnt[t] : 0u;
    sc[t] = v; __syncthreads();
    for (int off = 1; off < 512; off <<= 1) {
        unsigned a = (t >= off) ? sc[t - off] : 0u;
        __syncthreads();
        sc[t] += a;
        __syncthreads();
    }
    unsigned ex = sc[t] - v;   // exclusive prefix
    if (t <= NB) bbase[t] = ex;     // bbase[NB] = total
    if (t < NB) bcur[t] = ex;
    if (t == 511) rowptr[N_NODES] = sc[511];
}

// ---- CSR pass 3: LDS counting-sort 4096 edges by bucket, coalesced run flush ----
__global__ void k_bscatter(const int* __restrict__ src, const int* __restrict__ dst,
                           unsigned* __restrict__ bcur, unsigned* __restrict__ ebuf, int ne) {
    __shared__ unsigned hist[NB];
    __shared__ unsigned sc[512];
    __shared__ unsigned basel[NB];
    __shared__ unsigned lcur[NB];
    __shared__ unsigned gdst[NB];
    __shared__ unsigned sbuf[SCAT_ITEMS];
    __shared__ unsigned short sb[SCAT_ITEMS];
    int t = threadIdx.x;
    for (int i = t; i < NB; i += 256) hist[i] = 0u;
    __syncthreads();
    int base0 = blockIdx.x * SCAT_ITEMS;
    unsigned key[16]; int bk[16];
    #pragma unroll
    for (int k = 0; k < 16; ++k) {
        int i = base0 + k * 256 + t;
        if (i < ne) {
            int d = dst[i];
            bk[k] = d >> 8;
            key[k] = ((unsigned)(d & 255) << 24) | (unsigned)src[i];
            atomicAdd(&hist[bk[k]], 1u);
        } else bk[k] = -1;
    }
    __syncthreads();
    // scan hist (padded to 512) with 256 threads, 2 elems each
    {
        unsigned v0 = hist[t];
        unsigned v1 = (t + 256 < NB) ? hist[t + 256] : 0u;
        sc[t] = v0; sc[t + 256] = v1; __syncthreads();
        for (int off = 1; off < 512; off <<= 1) {
            unsigned a0 = (t >= off) ? sc[t - off] : 0u;
            unsigned a1 = (t + 256 >= off) ? sc[t + 256 - off] : 0u;
            __syncthreads();
            sc[t] += a0; sc[t + 256] += a1;
            __syncthreads();
        }
    }
    for (int i = t; i < NB; i += 256) {
        unsigned b0 = sc[i] - hist[i];
        basel[i] = b0; lcur[i] = b0;
    }
    __syncthreads();
    // reserve a contiguous global run per bucket (1 atomic per non-empty bucket)
    for (int i = t; i < NB; i += 256) if (hist[i]) gdst[i] = atomicAdd(&bcur[i], hist[i]);
    // sort items into LDS by bucket
    #pragma unroll
    for (int k = 0; k < 16; ++k) if (bk[k] >= 0) {
        unsigned p = atomicAdd(&lcur[bk[k]], 1u);
        sbuf[p] = key[k]; sb[p] = (unsigned short)bk[k];
    }
    __syncthreads();
    int cnt = min(SCAT_ITEMS, ne - base0);
    for (int j = t; j < cnt; j += 256) {
        unsigned b = sb[j];
        ebuf[gdst[b] + ((unsigned)j - basel[b])] = sbuf[j];
    }
}

// ---- CSR pass 4: one block per bucket -> deg/dinv/rowptr + col via LDS staging ----
__global__ void k_bcsr(const unsigned* __restrict__ ebuf, const unsigned* __restrict__ bbase,
                       unsigned* __restrict__ rowptr, float* __restrict__ dinv,
                       int* __restrict__ col, int n) {
    __shared__ unsigned deg[256];
    __shared__ unsigned sc[256];
    __shared__ unsigned lcur[256];
    __shared__ int colbuf[COLCAP];
    int b = blockIdx.x, t = threadIdx.x;
    int lo = b << 8;
    unsigned e0 = bbase[b], e1 = bbase[b + 1];
    deg[t] = 0u; __syncthreads();
    for (unsigned j = e0 + t; j < e1; j += 256) atomicAdd(&deg[ebuf[j] >> 24], 1u);
    __syncthreads();
    sc[t] = deg[t]; __syncthreads();
    for (int off = 1; off < 256; off <<= 1) {
        unsigned a = (t >= off) ? sc[t - off] : 0u;
        __syncthreads();
        sc[t] += a;
        __syncthreads();
    }
    unsigned lrp = sc[t] - deg[t];  // exclusive
    if (lo + t < n) {
        rowptr[lo + t] = e0 + lrp;
        dinv[lo + t] = rsqrtf((float)(deg[t] + 1u));  // +1 self loop
    }
    lcur[t] = lrp; __syncthreads();
    for (unsigned j = e0 + t; j < e1; j += 256) {
        unsigned k = ebuf[j];
        unsigned p = atomicAdd(&lcur[k >> 24], 1u);
        if (p < COLCAP) colbuf[p] = (int)(k & 0xFFFFFFu);
        else col[e0 + p] = (int)(k & 0xFFFFFFu);   // overflow fallback (statistically unreachable)
    }
    __syncthreads();
    unsigned cnt = e1 - e0;
    for (unsigned j = t; j < cnt && j < COLCAP; j += 256) col[e0 + j] = colbuf[j];
}

// p-normalize (block 0, wave 0) + zero the 65536-bin histogram (whole grid: 256x256)
__global__ void k_pnorm_zh(const float* __restrict__ p, float* __restrict__ pn,
                           unsigned* __restrict__ misc, unsigned* __restrict__ hist) {
    int g = blockIdx.x * blockDim.x + threadIdx.x;
    hist[g] = 0u;
    if (blockIdx.x == 0) {
        int t = threadIdx.x;
        if (t < 64) {
            float v = p[t];
            float s = v * v;
            for (int o = 32; o; o >>= 1) s += __shfl_down(s, o, 64);
            s = __shfl(s, 0, 64);
            pn[t] = v / (sqrtf(s) + 1e-8f);
        }
        if (t < 16) misc[t] = 0u;
    }
}

// wave per 4 rows (ILP): y[i] = dot(h[i,:], pn); histogram of top-16 bits of flipped key
__global__ void k_y_hist(const float* __restrict__ h, const float* __restrict__ pn,
                         float* __restrict__ y, unsigned* __restrict__ hist, int n) {
    int wave = (blockIdx.x * blockDim.x + threadIdx.x) >> 6;
    int lane = threadIdx.x & 63;
    int nw = (gridDim.x * blockDim.x) >> 6;
    float p = pn[lane];
    for (int i = wave; i < n; i += 4 * nw) {
        int i1 = i + nw, i2 = i + 2 * nw, i3 = i + 3 * nw;
        float v0 = h[(size_t)i * D + lane] * p;
        float v1 = (i1 < n) ? h[(size_t)i1 * D + lane] * p : 0.f;
        float v2 = (i2 < n) ? h[(size_t)i2 * D + lane] * p : 0.f;
        float v3 = (i3 < n) ? h[(size_t)i3 * D + lane] * p : 0.f;
        #pragma unroll
        for (int o = 32; o; o >>= 1) {
            v0 += __shfl_down(v0, o, 64);
            v1 += __shfl_down(v1, o, 64);
            v2 += __shfl_down(v2, o, 64);
            v3 += __shfl_down(v3, o, 64);
        }
        if (lane == 0) {
            y[i] = v0; atomicAdd(&hist[fkey(v0) >> 16], 1u);
            if (i1 < n) { y[i1] = v1; atomicAdd(&hist[fkey(v1) >> 16], 1u); }
            if (i2 < n) { y[i2] = v2; atomicAdd(&hist[fkey(v2) >> 16], 1u); }
            if (i3 < n) { y[i3] = v3; atomicAdd(&hist[fkey(v3) >> 16], 1u); }
        }
    }
}

// fused single-block: threshold search + compact (LDS) + top-32 select + Z gather
// exact jax.lax.top_k order (value desc, index asc)
__global__ void k_topsel(const unsigned* __restrict__ hist, const float* __restrict__ y,
                         unsigned long long* __restrict__ cand, const float* __restrict__ h,
                         float* __restrict__ z, int n) {
    __shared__ unsigned s64[1024];
    __shared__ unsigned long long scand[TCAP];
    __shared__ unsigned long long smax[1024];
    __shared__ unsigned scount;
    __shared__ unsigned sthr;
    __shared__ int sg;
    __shared__ int sidx[TOPK];
    __shared__ float swv[TOPK];
    int t = threadIdx.x;  // 1024 threads
    // --- phase 1: threshold (suffix sums over 1024 groups of 64 bins) ---
    unsigned gs = 0;
    #pragma unroll 8
    for (int j = 0; j < 64; ++j) gs += hist[t * 64 + j];
    s64[t] = gs; __syncthreads();
    for (int off = 1; off < 1024; off <<= 1) {
        unsigned add = (t + off < 1024) ? s64[t + off] : 0u;
        __syncthreads();
        s64[t] += add;
        __syncthreads();
    }
    if (s64[t] >= TOPK && (t == 1023 || s64[t + 1] < TOPK)) sg = t;
    __syncthreads();
    if (t == 0) {
        int g = sg;
        unsigned run = (g == 1023) ? 0u : s64[g + 1];
        unsigned thr = (unsigned)(g * 64);
        for (int i = 63; i >= 0; --i) {
            run += hist[g * 64 + i];
            if (run >= TOPK) { thr = (unsigned)(g * 64 + i); break; }
        }
        sthr = thr; scount = 0;
    }
    __syncthreads();
    unsigned thr = sthr;
    // --- phase 2: compact candidates (LDS; global fallback past TCAP) ---
    for (int i = t; i < n; i += 1024) {
        unsigned k = fkey(y[i]);
        if ((k >> 16) >= thr) {
            unsigned pos = atomicAdd(&scount, 1u);
            unsigned long long pk = ((unsigned long long)k << 32) | (unsigned)(0xFFFFFFFFu - (unsigned)i);
            if (pos < TCAP) scand[pos] = pk; else cand[pos] = pk;
        }
    }
    __syncthreads();
    int C = (int)scount;
    // --- phase 3: top-32 selection ---
    if (C <= 64) {
        if (t < 64) {
            unsigned long long mine = (t < C) ? scand[t] : 0ull;
            for (int k = 0; k < TOPK; ++k) {
                unsigned long long m = mine;
                for (int o = 32; o; o >>= 1) {
                    unsigned long long other = __shfl_down(m, o, 64);
                    if (other > m) m = other;
                }
                unsigned long long best = __shfl(m, 0, 64);
                if (mine == best) mine = 0ull;
                if (t == 0) {
                    int idx = (int)(0xFFFFFFFFu - (unsigned)(best & 0xFFFFFFFFull));
                    sidx[k] = idx;
                    swv[k] = tanhf(y[idx]);
                }
            }
        }
        __syncthreads();
    } else {
        for (int k = 0; k < TOPK; ++k) {
            unsigned long long m = 0ull;
            for (int j = t; j < C; j += 1024) {
                unsigned long long c = (j < TCAP) ? scand[j] : cand[j];
                if (c > m) m = c;
            }
            smax[t] = m; __syncthreads();
            for (int off = 512; off; off >>= 1) {
                if (t < off) { if (smax[t + off] > smax[t]) smax[t] = smax[t + off]; }
                __syncthreads();
            }
            unsigned long long best = smax[0];
            __syncthreads();
            for (int j = t; j < C; j += 1024) {
                if (j < TCAP) { if (scand[j] == best) scand[j] = 0ull; }
                else if (cand[j] == best) cand[j] = 0ull;
            }
            if (t == 0) {
                int idx = (int)(0xFFFFFFFFu - (unsigned)(best & 0xFFFFFFFFull));
                sidx[k] = idx;
                swv[k] = tanhf(y[idx]);
            }
            __syncthreads();
        }
    }
    // --- phase 4: z_flat gather ---
    for (int e = t; e < GIN; e += 1024) {
        int k = e & 31, d = e >> 5;
        z[e] = h[(size_t)sidx[k] * D + d] * swv[k];  // z_flat[d*32+k] = Z[k][d]
    }
}

// two independent matvecs (gi, gh) fused into one dispatch; seg by blockIdx
// out[r] = dot(W[r,:], vec) + bias[r]; vec = concat(vecA[:lenA], vecB)
__global__ void k_mv2(const float* __restrict__ W0, const float* __restrict__ bia0,
                      const float* __restrict__ vA0, int lenA0, const float* __restrict__ vB0,
                      float* __restrict__ out0, int cols0,
                      const float* __restrict__ W1, const float* __restrict__ bia1,
                      const float* __restrict__ vA1, int lenA1, const float* __restrict__ vB1,
                      float* __restrict__ out1, int cols1) {
    extern __shared__ float v[];
    int seg = (blockIdx.x >= MV_BLKS);
    const float* W    = seg ? W1   : W0;
    const float* bias = seg ? bia1 : bia0;
    const float* vA   = seg ? vA1  : vA0;
    const float* vB   = seg ? vB1  : vB0;
    float* out        = seg ? out1 : out0;
    int lenA          = seg ? lenA1 : lenA0;
    int cols          = seg ? cols1 : cols0;
    int lb = blockIdx.x - (seg ? MV_BLKS : 0);
    for (int j = threadIdx.x; j < cols; j += blockDim.x)
        v[j] = (j < lenA) ? vA[j] : vB[j - lenA];
    __syncthreads();
    int row = ((lb * blockDim.x + threadIdx.x) >> 6);
    int lane = threadIdx.x & 63;
    if (row >= GI3) return;
    const float4* Wr = (const float4*)(W + (size_t)row * cols);
    int n4 = cols >> 2;
    float acc = 0.f;
    for (int j = lane; j < n4; j += 64) {
        float4 w4 = Wr[j];
        acc += w4.x * v[4 * j] + w4.y * v[4 * j + 1] + w4.z * v[4 * j + 2] + w4.w * v[4 * j + 3];
    }
    for (int o = 32; o; o >>= 1) acc += __shfl_down(acc, o, 64);
    if (lane == 0) out[row] = acc + bias[row];
}

__global__ void k_gru(const float* __restrict__ gi, const float* __restrict__ gh,
                      const float* __restrict__ w, const float* __restrict__ b,
                      float* __restrict__ neww) {
    int j = blockIdx.x * blockDim.x + threadIdx.x;
    if (j >= NP) return;
    float r = 1.f / (1.f + expf(-(gi[j] + gh[j])));
    float z = 1.f / (1.f + expf(-(gi[NP + j] + gh[NP + j])));
    float n = tanhf(gi[2 * NP + j] + r * gh[2 * NP + j]);
    float h0 = (j < 4096) ? w[j] : b[j - 4096];
    neww[j] = (1.f - z) * n + z * h0;
}

// sxw[i][o] = dinv[i] * sum_d h[i][d] * neww[o*64+d]   (dinv folded into producer)
__global__ void k_xw(const float* __restrict__ h, const float* __restrict__ neww,
                     const float* __restrict__ dinv, float* __restrict__ sxw, int n) {
    __shared__ float WT[64 * 64];  // WT[d*64+o] = weight[o][d]
    for (int t = threadIdx.x; t < 4096; t += blockDim.x) {
        int o = t >> 6, d = t & 63;
        WT[d * 64 + o] = neww[t];
    }
    __syncthreads();
    int wave = (blockIdx.x * blockDim.x + threadIdx.x) >> 6;
    int lane = threadIdx.x & 63;
    int nw = (gridDim.x * blockDim.x) >> 6;
    for (int i = wave; i < n; i += nw) {
        float hv = h[(size_t)i * D + lane];
        float acc = 0.f;
        #pragma unroll 16
        for (int d = 0; d < 64; ++d) {
            float hd = __shfl(hv, d, 64);
            acc += hd * WT[d * 64 + lane];
        }
        sxw[(size_t)i * D + lane] = dinv[i] * acc;
    }
}

// wave per node: out[v][o] = bias[o] + dinv[v]*(sxw[v][o] + sum_e sxw[s][o])
// 8-way ILP over edges: 8 independent gathers in flight per inner iteration
__global__ void k_agg(const float* __restrict__ sxw, const float* __restrict__ dinv,
                      const unsigned* __restrict__ rowptr, const int* __restrict__ col,
                      const float* __restrict__ neww, float* __restrict__ out,
                      int n, int relu) {
    int wave = (blockIdx.x * blockDim.x + threadIdx.x) >> 6;
    int lane = threadIdx.x & 63;
    int nw = (gridDim.x * blockDim.x) >> 6;
    float bias = neww[4096 + lane];
    for (int v = wave; v < n; v += nw) {
        unsigned p0 = rowptr[v], p1 = rowptr[v + 1];
        float dv = dinv[v];
        float acc = sxw[(size_t)v * D + lane];
        float acc1 = 0.f;
        for (unsigned base = p0; base < p1; base += 64) {
            int cnt = (int)min(64u, p1 - base);
            int s = 0;
            if (lane < cnt) s = col[base + lane];
            int j = 0;
            for (; j + 8 <= cnt; j += 8) {
                int s0 = __shfl(s, j, 64);
                int s1 = __shfl(s, j + 1, 64);
                int s2 = __shfl(s, j + 2, 64);
                int s3 = __shfl(s, j + 3, 64);
                int s4 = __shfl(s, j + 4, 64);
                int s5 = __shfl(s, j + 5, 64);
                int s6 = __shfl(s, j + 6, 64);
                int s7 = __shfl(s, j + 7, 64);
                float a0 = sxw[(size_t)s0 * D + lane];
                float a1 = sxw[(size_t)s1 * D + lane];
                float a2 = sxw[(size_t)s2 * D + lane];
                float a3 = sxw[(size_t)s3 * D + lane];
                float a4 = sxw[(size_t)s4 * D + lane];
                float a5 = sxw[(size_t)s5 * D + lane];
                float a6 = sxw[(size_t)s6 * D + lane];
                float a7 = sxw[(size_t)s7 * D + lane];
                acc  += (a0 + a2) + (a4 + a6);
                acc1 += (a1 + a3) + (a5 + a7);
            }
            for (; j < cnt; ++j)
                acc += sxw[(size_t)__shfl(s, j, 64) * D + lane];
        }
        float r = bias + dv * (acc + acc1);
        if (relu) r = fmaxf(r, 0.f);
        out[(size_t)v * D + lane] = r;
    }
}

extern "C" void kernel_launch(void* const* d_in, const int* in_sizes, int n_in,
                              void* d_out, int out_size, void* d_ws, size_t ws_size,
                              hipStream_t stream) {
    if (ws_size < (size_t)WS_FLOATS * 4) return;  // workspace too small: fail cleanly

    const float* x = (const float*)d_in[0];
    const int* src = (const int*)d_in[1];
    const int* dst = src + N_EDGES;
    const float* P[2]   = {(const float*)d_in[2],  (const float*)d_in[3]};
    const float* W[2]   = {(const float*)d_in[4],  (const float*)d_in[6]};
    const float* B[2]   = {(const float*)d_in[5],  (const float*)d_in[7]};
    const float* WIH[2] = {(const float*)d_in[8],  (const float*)d_in[12]};
    const float* WHH[2] = {(const float*)d_in[9],  (const float*)d_in[13]};
    const float* BIH[2] = {(const float*)d_in[10], (const float*)d_in[14]};
    const float* BHH[2] = {(const float*)d_in[11], (const float*)d_in[15]};

    float* ws = (float*)d_ws;
    float* pn = ws + OFF_PN;
    unsigned* misc = (unsigned*)(ws + OFF_MISC);
    float* zflat = ws + OFF_ZFLAT;
    float* neww = ws + OFF_NEWW;
    float* gi = ws + OFF_GI;
    float* gh = ws + OFF_GH;
    unsigned* hist = (unsigned*)(ws + OFF_HIST);
    float* y = ws + OFF_Y;
    unsigned* bcnt  = (unsigned*)(ws + OFF_DEG);
    unsigned* bbase = (unsigned*)(ws + OFF_DEG) + 512;
    unsigned* bcur  = (unsigned*)(ws + OFF_DEG) + 1024;
    float* dinv = ws + OFF_DINV;
    unsigned* rowptr = (unsigned*)(ws + OFF_ROWPTR);
    int* col = (int*)(ws + OFF_COL);
    unsigned long long* cand = (unsigned long long*)(ws + OFF_CAND);
    float* xw = ws + OFF_XW;
    unsigned* ebuf = (unsigned*)(ws + OFF_XW);  // overlays xw; dead before k_xw runs
    float* h1 = ws + OFF_H1;
    float* out = (float*)d_out;

    // ---- bucketed CSR build (shared by both layers) ----
    hipLaunchKernelGGL(k_zero32, dim3((NB + 255) / 256), dim3(256), 0, stream, bcnt, NB);
    hipLaunchKernelGGL(k_bcount, dim3(SCAT_BLKS), dim3(256), 0, stream, dst, bcnt, N_EDGES);
    hipLaunchKernelGGL(k_bscan, dim3(1), dim3(512), 0, stream, bcnt, bbase, bcur, rowptr);
    hipLaunchKernelGGL(k_bscatter, dim3(SCAT_BLKS), dim3(256), 0, stream, src, dst, bcur, ebuf, N_EDGES);
    hipLaunchKernelGGL(k_bcsr, dim3(NB), dim3(256), 0, stream, ebuf, bbase, rowptr, dinv, col, N_NODES);

    for (int l = 0; l < 2; ++l) {
        const float* h = (l == 0) ? x : h1;
        float* ho = (l == 0) ? h1 : out;
        hipLaunchKernelGGL(k_pnorm_zh, dim3(256), dim3(256), 0, stream, P[l], pn, misc, hist);
        hipLaunchKernelGGL(k_y_hist, dim3(1024), dim3(256), 0, stream, h, pn, y, hist, N_NODES);
        hipLaunchKernelGGL(k_topsel, dim3(1), dim3(1024), 0, stream, hist, y, cand, h, zflat, N_NODES);
        hipLaunchKernelGGL(k_mv2, dim3(2 * MV_BLKS), dim3(256), NP * 4, stream,
                           WIH[l], BIH[l], zflat, GIN, zflat, gi, GIN,
                           WHH[l], BHH[l], W[l], 4096, B[l], gh, NP);
        hipLaunchKernelGGL(k_gru, dim3((NP + 255) / 256), dim3(256), 0, stream, gi, gh, W[l], B[l], neww);
        hipLaunchKernelGGL(k_xw, dim3(2048), dim3(256), 0, stream, h, neww, dinv, xw, N_NODES);
        hipLaunchKernelGGL(k_agg, dim3(4096), dim3(256), 0, stream, xw, dinv, rowptr, col, neww, ho,
                           N_NODES, (l == 0) ? 1 : 0);
    }
}